// Round 4
// baseline (400.874 us; speedup 1.0000x reference)
//
#include <hip/hip_runtime.h>

// Problem dims (fixed)
#define S_ 256
#define BSZ_ 64
#define IN_F_ 1024
#define OUT_F_ 512
#define USER_F_ 512

typedef short short8 __attribute__((ext_vector_type(8)));
typedef float f32x4 __attribute__((ext_vector_type(4)));

__device__ __forceinline__ ushort f2bf(float f) {
  unsigned u = __float_as_uint(f);
  unsigned r = (u + 0x7FFFu + ((u >> 16) & 1u)) >> 16;
  return (ushort)r;
}
__device__ __forceinline__ float bf2f(unsigned hi16) {
  return __uint_as_float(hi16 << 16);
}
__device__ __forceinline__ float sigf(float x) {
  return 1.f / (1.f + __expf(-x));
}
__device__ __forceinline__ float tanh_safe(float x) {
  float ax = fabsf(x);
  float e = __expf(-2.f * ax);
  float r = (1.f - e) / (1.f + e);
  return copysignf(r, x);
}

// Raw workgroup barrier: DS ops are in-order per wave; lgkmcnt(0) before
// s_barrier makes each wave's ds_write/ds_read complete, so LDS is coherent
// CU-wide after the barrier. Crucially: NO vmcnt(0) drain — outstanding
// global prefetch loads stay in flight across the barrier (the thing
// __syncthreads() forbids). "memory" clobber pins compiler ordering.
__device__ __forceinline__ void wg_barrier_lds() {
  asm volatile("s_waitcnt lgkmcnt(0)" ::: "memory");
  __builtin_amdgcn_s_barrier();
}

// ---------------- conversion kernels ----------------
__global__ void convert_bf16(const float* __restrict__ in, ushort* __restrict__ out, long n) {
  long i = ((long)blockIdx.x * blockDim.x + threadIdx.x) * 4;
  if (i + 3 < n) {
    float4 v = *(const float4*)(in + i);
    ushort4 o;
    o.x = f2bf(v.x); o.y = f2bf(v.y); o.z = f2bf(v.z); o.w = f2bf(v.w);
    *(ushort4*)(out + i) = o;
  }
}

// out[e*512+d] = bf16(W[d*512+e])
__global__ void convert_transpose_w(const float* __restrict__ in, ushort* __restrict__ out) {
  int i = blockIdx.x * blockDim.x + threadIdx.x;
  int e = i >> 9, d = i & 511;
  out[i] = f2bf(in[d * 512 + e]);
}

__global__ void zerof(float* __restrict__ p, int n) {
  int i = blockIdx.x * 256 + threadIdx.x;
  if (i < n) p[i] = 0.f;
}

// ---------------- register-staged tile machinery (128x64 bf16 = 16KB) -------
// thread t: row = t>>1, half h = t&1 -> 64B contiguous global (4x dwordx4).
// LDS: row stride 64 shorts; 16B-chunk c at phys pc = c ^ (row&7) -> ds_read_b128
// conflict-free (proven 0 conflicts in R3), ds_write spread across banks.
struct Stg { uint4 v[4]; };

__device__ __forceinline__ void ld_tile(Stg& s, const ushort* __restrict__ g,
                                        int K, int t) {
  const int row = t >> 1, h = t & 1;
  const uint4* p = (const uint4*)(g + (long)row * K + h * 32);
  s.v[0] = p[0]; s.v[1] = p[1]; s.v[2] = p[2]; s.v[3] = p[3];
}
__device__ __forceinline__ void st_tile(const Stg& s, ushort* lds, int t) {
  const int row = t >> 1, h = t & 1;
  ushort* base = lds + row * 64;
#pragma unroll
  for (int i = 0; i < 4; ++i) {
    int pc = (h * 4 + i) ^ (row & 7);
    *(uint4*)(base + pc * 8) = s.v[i];
  }
}

__device__ __forceinline__ short8 frag(const ushort* lds, int row, int kk, int q) {
  int pc = (kk * 4 + q) ^ (row & 7);
  return *(const short8*)(lds + row * 64 + pc * 8);
}

__device__ __forceinline__ void compute_step(const ushort* As, const ushort* Bs,
                                             f32x4 acc[4][4], int wr, int wc,
                                             int mlane, int q) {
#pragma unroll
  for (int kk = 0; kk < 2; ++kk) {
    short8 af[4], bfr[4];
#pragma unroll
    for (int r = 0; r < 4; ++r) af[r] = frag(As, wr * 64 + r * 16 + mlane, kk, q);
#pragma unroll
    for (int c = 0; c < 4; ++c) bfr[c] = frag(Bs, wc * 64 + c * 16 + mlane, kk, q);
#pragma unroll
    for (int r = 0; r < 4; ++r)
#pragma unroll
      for (int c = 0; c < 4; ++c)
        acc[r][c] = __builtin_amdgcn_mfma_f32_16x16x32_bf16(af[r], bfr[c], acc[r][c], 0, 0, 0);
  }
}

// Register-staged dbuf K-loop, BK=64, raw barriers. Global loads for tile k+2
// are issued a full compute-phase before their ds_write consumes them, and no
// barrier drains vmcnt -> latency covered. NSTEP even.
template <int NSTEP>
__device__ __forceinline__ void gemm_loop_rs(const ushort* __restrict__ A,
                                             const ushort* __restrict__ B, int K,
                                             ushort* As0, ushort* Bs0,
                                             ushort* As1, ushort* Bs1,
                                             f32x4 acc[4][4], int t,
                                             int wr, int wc, int mlane, int q) {
  Stg a0, b0, a1, b1;
  ld_tile(a0, A, K, t); ld_tile(b0, B, K, t);
  st_tile(a0, As0, t);  st_tile(b0, Bs0, t);
  ld_tile(a1, A + 64, K, t); ld_tile(b1, B + 64, K, t);
  wg_barrier_lds();
#pragma unroll 1
  for (int k = 0; k < NSTEP; k += 2) {
    // fill buf1 with tile k+1; compute tile k from buf0
    st_tile(a1, As1, t); st_tile(b1, Bs1, t);
    if (k + 2 < NSTEP) {
      ld_tile(a0, A + (k + 2) * 64, K, t);
      ld_tile(b0, B + (k + 2) * 64, K, t);
    }
    compute_step(As0, Bs0, acc, wr, wc, mlane, q);
    wg_barrier_lds();
    // fill buf0 with tile k+2; compute tile k+1 from buf1
    if (k + 2 < NSTEP) {
      st_tile(a0, As0, t); st_tile(b0, Bs0, t);
      if (k + 3 < NSTEP) {
        ld_tile(a1, A + (k + 3) * 64, K, t);
        ld_tile(b1, B + (k + 3) * 64, K, t);
      }
    }
    compute_step(As1, Bs1, acc, wr, wc, mlane, q);
    wg_barrier_lds();
  }
}

#define ACC_ZERO(a)                         \
  _Pragma("unroll") for (int r = 0; r < 4; ++r) \
  _Pragma("unroll") for (int c = 0; c < 4; ++c) { \
    a[r][c][0] = 0.f; a[r][c][1] = 0.f; a[r][c][2] = 0.f; a[r][c][3] = 0.f; }

// ---------------- fused d/u GEMM + gating ----------------
// grid: flat 512. XCD swizzle: i%8 = XCD (round-robin assumption); give each
// XCD a contiguous y-range so the 4 x-blocks sharing an A-strip hit one L2.
__global__ __launch_bounds__(256, 2) void gemm_du(
    const ushort* __restrict__ Xd, const ushort* __restrict__ Wd,
    const float* __restrict__ bd,
    const ushort* __restrict__ Xu, const ushort* __restrict__ Wu,
    const float* __restrict__ bu,
    ushort* __restrict__ dg, ushort* __restrict__ ug) {
  __shared__ ushort sm[32768];  // 64KB: As0 Bs0 As1 Bs1
  ushort* As0 = sm; ushort* Bs0 = sm + 8192;
  ushort* As1 = sm + 16384; ushort* Bs1 = sm + 24576;
  const int i = blockIdx.x;
  const int k8 = i & 7, j = i >> 3;
  const int by = k8 * 16 + (j >> 2), bx = j & 3;   // y in [k8*16, k8*16+16)
  const int tid = threadIdx.x, lane = tid & 63, w = tid >> 6;
  const int wr = w >> 1, wc = w & 1, mlane = lane & 15, q = lane >> 4;
  const int m0 = by * 128, n0 = bx * 128;

  f32x4 accd[4][4]; ACC_ZERO(accd);
  gemm_loop_rs<16>(Xd + (long)m0 * 1024, Wd + (long)n0 * 1024, 1024,
                   As0, Bs0, As1, Bs1, accd, tid, wr, wc, mlane, q);
  f32x4 accu[4][4]; ACC_ZERO(accu);
  gemm_loop_rs<8>(Xu + (long)m0 * 512, Wu + (long)n0 * 512, 512,
                  As0, Bs0, As1, Bs1, accu, tid, wr, wc, mlane, q);

#pragma unroll
  for (int c = 0; c < 4; ++c) {
    const int gn = n0 + wc * 64 + c * 16 + mlane;
    const float bdv = bd[gn], buv = bu[gn];
#pragma unroll
    for (int r = 0; r < 4; ++r)
#pragma unroll
      for (int ii = 0; ii < 4; ++ii) {
        const int gm = m0 + wr * 64 + r * 16 + q * 4 + ii;
        const long idx = (long)gm * OUT_F_ + gn;
        float dp = accd[r][c][ii] + bdv;
        float up = accu[r][c][ii] + buv;
        float dgv = dp * sigf(up);
        float ugv = up * sigf(dgv);
        dg[idx] = f2bf(dgv);
        ug[idx] = f2bf(ugv);
      }
  }
}

// ---------------- t = dg * Wt^T ----------------
__global__ __launch_bounds__(256, 2) void gemm_t(
    const ushort* __restrict__ dgp, const ushort* __restrict__ Wt,
    ushort* __restrict__ tout) {
  __shared__ ushort sm[32768];
  ushort* As0 = sm; ushort* Bs0 = sm + 8192;
  ushort* As1 = sm + 16384; ushort* Bs1 = sm + 24576;
  const int i = blockIdx.x;
  const int k8 = i & 7, j = i >> 3;
  const int by = k8 * 16 + (j >> 2), bx = j & 3;
  const int tid = threadIdx.x, lane = tid & 63, w = tid >> 6;
  const int wr = w >> 1, wc = w & 1, mlane = lane & 15, q = lane >> 4;
  const int m0 = by * 128, n0 = bx * 128;

  f32x4 acc[4][4]; ACC_ZERO(acc);
  gemm_loop_rs<8>(dgp + (long)m0 * 512, Wt + (long)n0 * 512, 512,
                  As0, Bs0, As1, Bs1, acc, tid, wr, wc, mlane, q);

#pragma unroll
  for (int c = 0; c < 4; ++c) {
    const int gn = n0 + wc * 64 + c * 16 + mlane;
#pragma unroll
    for (int r = 0; r < 4; ++r)
#pragma unroll
      for (int ii = 0; ii < 4; ++ii) {
        const int gm = m0 + wr * 64 + r * 16 + q * 4 + ii;
        tout[(long)gm * OUT_F_ + gn] = f2bf(acc[r][c][ii]);
      }
  }
}

// ---------------- att tile + tanh + row/col sums (att never materialized) ----
__global__ __launch_bounds__(256, 2) void gemm_att(
    const ushort* __restrict__ t, const ushort* __restrict__ ug,
    float* __restrict__ rowlog, float* __restrict__ collog) {
  __shared__ ushort sm[32768];
  ushort* As0 = sm; ushort* Bs0 = sm + 8192;
  ushort* As1 = sm + 16384; ushort* Bs1 = sm + 24576;
  const int i = blockIdx.x;
  const int k8 = i & 7, j = i >> 3;          // j in [0,32)
  const int b = k8 * 8 + (j >> 2);           // 8 batches per XCD
  const int by = (j >> 1) & 1, bx = j & 1;
  const int tid = threadIdx.x, lane = tid & 63, w = tid >> 6;
  const int wr = w >> 1, wc = w & 1, mlane = lane & 15, q = lane >> 4;
  const ushort* A = t + (long)b * (S_ * OUT_F_) + (long)by * 128 * 512;
  const ushort* B = ug + (long)b * (S_ * OUT_F_) + (long)bx * 128 * 512;

  f32x4 acc[4][4]; ACC_ZERO(acc);
  gemm_loop_rs<8>(A, B, 512, As0, Bs0, As1, Bs1, acc, tid, wr, wc, mlane, q);

  float rs[4][4], cs[4];
#pragma unroll
  for (int r = 0; r < 4; ++r)
#pragma unroll
    for (int ii = 0; ii < 4; ++ii) rs[r][ii] = 0.f;
#pragma unroll
  for (int c = 0; c < 4; ++c) cs[c] = 0.f;
#pragma unroll
  for (int r = 0; r < 4; ++r)
#pragma unroll
    for (int c = 0; c < 4; ++c)
#pragma unroll
      for (int ii = 0; ii < 4; ++ii) {
        float v = tanh_safe(acc[r][c][ii]);
        rs[r][ii] += v;
        cs[c] += v;
      }
#pragma unroll
  for (int m = 1; m < 16; m <<= 1)
#pragma unroll
    for (int r = 0; r < 4; ++r)
#pragma unroll
      for (int ii = 0; ii < 4; ++ii) rs[r][ii] += __shfl_xor(rs[r][ii], m, 64);
#pragma unroll
  for (int m = 16; m < 64; m <<= 1)
#pragma unroll
    for (int c = 0; c < 4; ++c) cs[c] += __shfl_xor(cs[c], m, 64);

  float* rsum = (float*)sm;
  float* csum = ((float*)sm) + 128;
  __syncthreads();  // full drain once; LDS tiles dead, safe to alias
  if (tid < 128) rsum[tid] = 0.f;
  else if (tid < 256) csum[tid - 128] = 0.f;
  __syncthreads();
  if (mlane == 0) {
#pragma unroll
    for (int r = 0; r < 4; ++r)
#pragma unroll
      for (int ii = 0; ii < 4; ++ii)
        atomicAdd(&rsum[wr * 64 + r * 16 + q * 4 + ii], rs[r][ii]);
  }
  if (q == 0) {
#pragma unroll
    for (int c = 0; c < 4; ++c) atomicAdd(&csum[wc * 64 + c * 16 + mlane], cs[c]);
  }
  __syncthreads();
  if (tid < 128)
    atomicAdd(&rowlog[b * S_ + by * 128 + tid], rsum[tid]);
  else if (tid < 256)
    atomicAdd(&collog[b * S_ + bx * 128 + (tid - 128)], csum[tid - 128]);
}

// ---------------- finalize ----------------
__device__ __forceinline__ float block_max(float v, float* buf, int tid) {
  buf[tid] = v; __syncthreads();
  for (int s = 128; s > 0; s >>= 1) {
    if (tid < s) buf[tid] = fmaxf(buf[tid], buf[tid + s]);
    __syncthreads();
  }
  float r = buf[0]; __syncthreads();
  return r;
}
__device__ __forceinline__ float block_sum(float v, float* buf, int tid) {
  buf[tid] = v; __syncthreads();
  for (int s = 128; s > 0; s >>= 1) {
    if (tid < s) buf[tid] = buf[tid] + buf[tid + s];
    __syncthreads();
  }
  float r = buf[0]; __syncthreads();
  return r;
}

__global__ __launch_bounds__(256) void finalize(
    const float* __restrict__ rowlog, const float* __restrict__ collog,
    const ushort* __restrict__ dg, const ushort* __restrict__ ug,
    float* __restrict__ out) {
  __shared__ float sd[S_], su[S_], buf[S_];
  const int b = blockIdx.x, tid = threadIdx.x;

  const float rowmean = rowlog[b * S_ + tid] * (1.f / (float)S_);
  const float colmean = collog[b * S_ + tid] * (1.f / (float)S_);

  float md = block_max(rowmean, buf, tid);
  float ed = __expf(rowmean - md);
  float sds = block_sum(ed, buf, tid);
  sd[tid] = ed / sds;
  float mu = block_max(colmean, buf, tid);
  float eu = __expf(colmean - mu);
  float sus = block_sum(eu, buf, tid);
  su[tid] = eu / sus;
  __syncthreads();

  const ushort* dgb = dg + (long)b * (S_ * OUT_F_);
  const ushort* ugb = ug + (long)b * (S_ * OUT_F_);
  float ad0 = 0.f, ad1 = 0.f, au0 = 0.f, au1 = 0.f;
  const int o = 2 * tid;
  for (int s = 0; s < S_; ++s) {
    const float wd = sd[s], wu = su[s];
    unsigned dv = *(const unsigned*)(dgb + s * OUT_F_ + o);
    unsigned uv = *(const unsigned*)(ugb + s * OUT_F_ + o);
    ad0 += wd * bf2f(dv & 0xffffu); ad1 += wd * bf2f(dv >> 16);
    au0 += wu * bf2f(uv & 0xffffu); au1 += wu * bf2f(uv >> 16);
  }
  out[b * OUT_F_ + o] = ad0;
  out[b * OUT_F_ + o + 1] = ad1;
  out[BSZ_ * OUT_F_ + b * OUT_F_ + o] = au0;
  out[BSZ_ * OUT_F_ + b * OUT_F_ + o + 1] = au1;
}

extern "C" void kernel_launch(void* const* d_in, const int* in_sizes, int n_in,
                              void* d_out, int out_size, void* d_ws, size_t ws_size,
                              hipStream_t stream) {
  (void)in_sizes; (void)n_in; (void)out_size; (void)ws_size;
  const float* Xd = (const float*)d_in[0];
  const float* Xu = (const float*)d_in[1];
  const float* Wd = (const float*)d_in[2];
  const float* bd = (const float*)d_in[3];
  const float* Wu = (const float*)d_in[4];
  const float* bu = (const float*)d_in[5];
  const float* W  = (const float*)d_in[6];
  float* out = (float*)d_out;
  char* ws = (char*)d_ws;

  ushort* Xd_bf  = (ushort*)(ws + 0L);
  ushort* Xu_bf  = (ushort*)(ws + 33554432L);
  ushort* Wd_bf  = (ushort*)(ws + 50331648L);
  ushort* Wu_bf  = (ushort*)(ws + 51380224L);
  ushort* Wt_bf  = (ushort*)(ws + 51904512L);
  ushort* dg     = (ushort*)(ws + 52428800L);
  ushort* ug     = (ushort*)(ws + 69206016L);
  ushort* t_bf   = (ushort*)(ws + 85983232L);
  float*  rowlog = (float*)(ws + 102760448L);
  float*  collog = (float*)(ws + 102825984L);

  convert_bf16<<<16384, 256, 0, stream>>>(Xd, Xd_bf, 16777216L);
  convert_bf16<<<8192, 256, 0, stream>>>(Xu, Xu_bf, 8388608L);
  convert_bf16<<<512, 256, 0, stream>>>(Wd, Wd_bf, 524288L);
  convert_bf16<<<256, 256, 0, stream>>>(Wu, Wu_bf, 262144L);
  convert_transpose_w<<<1024, 256, 0, stream>>>(W, Wt_bf);
  zerof<<<128, 256, 0, stream>>>(rowlog, 32768);

  dim3 blk(256);
  gemm_du<<<512, blk, 0, stream>>>(Xd_bf, Wd_bf, bd, Xu_bf, Wu_bf, bu, dg, ug);
  gemm_t<<<512, blk, 0, stream>>>(dg, Wt_bf, t_bf);
  gemm_att<<<256, blk, 0, stream>>>(t_bf, ug, rowlog, collog);
  finalize<<<64, 256, 0, stream>>>(rowlog, collog, dg, ug, out);
}

// Round 5
// 223.594 us; speedup vs baseline: 1.7929x; 1.7929x over previous
//
#include <hip/hip_runtime.h>

// Problem dims (fixed)
#define S_ 256
#define BSZ_ 64
#define IN_F_ 1024
#define OUT_F_ 512
#define USER_F_ 512

typedef short short8 __attribute__((ext_vector_type(8)));
typedef float f32x4 __attribute__((ext_vector_type(4)));

__device__ __forceinline__ ushort f2bf(float f) {
  unsigned u = __float_as_uint(f);
  unsigned r = (u + 0x7FFFu + ((u >> 16) & 1u)) >> 16;
  return (ushort)r;
}
__device__ __forceinline__ float bf2f(unsigned hi16) {
  return __uint_as_float(hi16 << 16);
}
__device__ __forceinline__ float sigf(float x) {
  return 1.f / (1.f + __expf(-x));
}
__device__ __forceinline__ float tanh_safe(float x) {
  float ax = fabsf(x);
  float e = __expf(-2.f * ax);
  float r = (1.f - e) / (1.f + e);
  return copysignf(r, x);
}

// async global->LDS, 16B per lane; LDS dest = wave-uniform base + lane*16
__device__ __forceinline__ void gl_lds16(const ushort* g, ushort* l) {
  __builtin_amdgcn_global_load_lds(
      (const __attribute__((address_space(1))) void*)g,
      (__attribute__((address_space(3))) void*)l, 16, 0, 0);
}

// ---------------- conversion kernels ----------------
__global__ void convert_bf16(const float* __restrict__ in, ushort* __restrict__ out, long n) {
  long i = ((long)blockIdx.x * blockDim.x + threadIdx.x) * 4;
  if (i + 3 < n) {
    float4 v = *(const float4*)(in + i);
    ushort4 o;
    o.x = f2bf(v.x); o.y = f2bf(v.y); o.z = f2bf(v.z); o.w = f2bf(v.w);
    *(ushort4*)(out + i) = o;
  }
}

// out[e*512+d] = bf16(W[d*512+e])
__global__ void convert_transpose_w(const float* __restrict__ in, ushort* __restrict__ out) {
  int i = blockIdx.x * blockDim.x + threadIdx.x;
  int e = i >> 9, d = i & 511;
  out[i] = f2bf(in[d * 512 + e]);
}

__global__ void zerof(float* __restrict__ p, int n) {
  int i = blockIdx.x * 256 + threadIdx.x;
  if (i < n) p[i] = 0.f;
}

// ---------------- tile staging (R3-proven: global_load_lds + XOR swizzle) ----
// LDS row stride 64 shorts; 16B-chunk c of row r stored at phys slot c^(r&7)
// by loading global chunk gc = c^(r&7) into lds slot c (lane-contiguous dest
// preserved). ds_read_b128 then conflict-free (0 conflicts measured in R3).
template <int ROWS>
__device__ __forceinline__ void stage_tile(const ushort* __restrict__ g, int K,
                                           ushort* lds, int w, int lane) {
  const int rin = lane >> 3;  // 0..7
  const int c = lane & 7;     // 16B chunk slot within row
#pragma unroll
  for (int i = 0; i < ROWS / 32; ++i) {
    int r = w * (ROWS / 4) + i * 8 + rin;
    int gc = c ^ (r & 7);
    gl_lds16(g + (long)r * K + gc * 8, lds + w * (ROWS / 4) * 64 + i * 512);
  }
}

__device__ __forceinline__ short8 frag(const ushort* lds, int row, int kk, int q) {
  int pc = (kk * 4 + q) ^ (row & 7);
  return *(const short8*)(lds + row * 64 + pc * 8);
}

// BM=64 x BN=128, 4 waves as 2x2 (wave tile 32x64): acc[2][4]
__device__ __forceinline__ void compute_step(const ushort* As, const ushort* Bs,
                                             f32x4 acc[2][4], int wr, int wc,
                                             int mlane, int q) {
#pragma unroll
  for (int kk = 0; kk < 2; ++kk) {
    short8 af[2], bfr[4];
#pragma unroll
    for (int r = 0; r < 2; ++r) af[r] = frag(As, wr * 32 + r * 16 + mlane, kk, q);
#pragma unroll
    for (int c = 0; c < 4; ++c) bfr[c] = frag(Bs, wc * 64 + c * 16 + mlane, kk, q);
#pragma unroll
    for (int r = 0; r < 2; ++r)
#pragma unroll
      for (int c = 0; c < 4; ++c)
        acc[r][c] = __builtin_amdgcn_mfma_f32_16x16x32_bf16(af[r], bfr[c], acc[r][c], 0, 0, 0);
  }
}

// single-buffer K-loop, BK=64: stage -> sync -> compute -> sync
template <int NSTEP>
__device__ __forceinline__ void gemm_loop(const ushort* __restrict__ A,
                                          const ushort* __restrict__ B, int K,
                                          ushort* As, ushort* Bs, f32x4 acc[2][4],
                                          int w, int lane, int wr, int wc,
                                          int mlane, int q) {
#pragma unroll 1
  for (int k = 0; k < NSTEP; ++k) {
    stage_tile<64>(A + k * 64, K, As, w, lane);
    stage_tile<128>(B + k * 64, K, Bs, w, lane);
    __syncthreads();
    compute_step(As, Bs, acc, wr, wc, mlane, q);
    __syncthreads();
  }
}

#define ACC_ZERO(a)                             \
  _Pragma("unroll") for (int r = 0; r < 2; ++r) \
  _Pragma("unroll") for (int c = 0; c < 4; ++c) { \
    a[r][c][0] = 0.f; a[r][c][1] = 0.f; a[r][c][2] = 0.f; a[r][c][3] = 0.f; }

// ---------------- fused d/u GEMM + gating ----------------
// grid 1024 flat. XCD swizzle: i&7 = XCD; 4 x-blocks sharing an A-strip are
// consecutive j on one XCD -> A-strip fetched ~once per XCD L2.
__global__ __launch_bounds__(256, 4) void gemm_du(
    const ushort* __restrict__ Xd, const ushort* __restrict__ Wd,
    const float* __restrict__ bd,
    const ushort* __restrict__ Xu, const ushort* __restrict__ Wu,
    const float* __restrict__ bu,
    ushort* __restrict__ dg, ushort* __restrict__ ug) {
  __shared__ ushort sm[12288];  // As 64x64 (4096) + Bs 128x64 (8192) = 24KB
  ushort* As = sm; ushort* Bs = sm + 4096;
  const int i = blockIdx.x;
  const int k8 = i & 7, j = i >> 3;           // j in [0,128)
  const int by = k8 * 32 + (j >> 2), bx = j & 3;
  const int tid = threadIdx.x, lane = tid & 63, w = tid >> 6;
  const int wr = w >> 1, wc = w & 1, mlane = lane & 15, q = lane >> 4;
  const int m0 = by * 64, n0 = bx * 128;

  f32x4 accd[2][4]; ACC_ZERO(accd);
  gemm_loop<16>(Xd + (long)m0 * 1024, Wd + (long)n0 * 1024, 1024,
                As, Bs, accd, w, lane, wr, wc, mlane, q);
  f32x4 accu[2][4]; ACC_ZERO(accu);
  gemm_loop<8>(Xu + (long)m0 * 512, Wu + (long)n0 * 512, 512,
               As, Bs, accu, w, lane, wr, wc, mlane, q);

#pragma unroll
  for (int c = 0; c < 4; ++c) {
    const int gn = n0 + wc * 64 + c * 16 + mlane;
    const float bdv = bd[gn], buv = bu[gn];
#pragma unroll
    for (int r = 0; r < 2; ++r)
#pragma unroll
      for (int ii = 0; ii < 4; ++ii) {
        const int gm = m0 + wr * 32 + r * 16 + q * 4 + ii;
        const long idx = (long)gm * OUT_F_ + gn;
        float dp = accd[r][c][ii] + bdv;
        float up = accu[r][c][ii] + buv;
        float dgv = dp * sigf(up);
        float ugv = up * sigf(dgv);
        dg[idx] = f2bf(dgv);
        ug[idx] = f2bf(ugv);
      }
  }
}

// ---------------- t = dg * Wt^T ----------------
__global__ __launch_bounds__(256, 4) void gemm_t(
    const ushort* __restrict__ dgp, const ushort* __restrict__ Wt,
    ushort* __restrict__ tout) {
  __shared__ ushort sm[12288];
  ushort* As = sm; ushort* Bs = sm + 4096;
  const int i = blockIdx.x;
  const int k8 = i & 7, j = i >> 3;
  const int by = k8 * 32 + (j >> 2), bx = j & 3;
  const int tid = threadIdx.x, lane = tid & 63, w = tid >> 6;
  const int wr = w >> 1, wc = w & 1, mlane = lane & 15, q = lane >> 4;
  const int m0 = by * 64, n0 = bx * 128;

  f32x4 acc[2][4]; ACC_ZERO(acc);
  gemm_loop<8>(dgp + (long)m0 * 512, Wt + (long)n0 * 512, 512,
               As, Bs, acc, w, lane, wr, wc, mlane, q);

#pragma unroll
  for (int c = 0; c < 4; ++c) {
    const int gn = n0 + wc * 64 + c * 16 + mlane;
#pragma unroll
    for (int r = 0; r < 2; ++r)
#pragma unroll
      for (int ii = 0; ii < 4; ++ii) {
        const int gm = m0 + wr * 32 + r * 16 + q * 4 + ii;
        tout[(long)gm * OUT_F_ + gn] = f2bf(acc[r][c][ii]);
      }
  }
}

// ---------------- att tile + tanh + row/col sums (att never materialized) ----
// per batch: 4 y-strips (64 rows) x 2 x-strips (128 cols) = 8 blocks; 512 total.
__global__ __launch_bounds__(256, 4) void gemm_att(
    const ushort* __restrict__ t, const ushort* __restrict__ ug,
    float* __restrict__ rowlog, float* __restrict__ collog) {
  __shared__ ushort sm[12288];
  ushort* As = sm; ushort* Bs = sm + 4096;
  const int i = blockIdx.x;
  const int k8 = i & 7, j = i >> 3;           // j in [0,64)
  const int b = k8 * 8 + (j >> 3);            // 8 batches per XCD
  const int l = j & 7, by = l >> 1, bx = l & 1;
  const int tid = threadIdx.x, lane = tid & 63, w = tid >> 6;
  const int wr = w >> 1, wc = w & 1, mlane = lane & 15, q = lane >> 4;
  const ushort* A = t + (long)b * (S_ * OUT_F_) + (long)by * 64 * 512;
  const ushort* B = ug + (long)b * (S_ * OUT_F_) + (long)bx * 128 * 512;

  f32x4 acc[2][4]; ACC_ZERO(acc);
  gemm_loop<8>(A, B, 512, As, Bs, acc, w, lane, wr, wc, mlane, q);

  float rs[2][4], cs[4];
#pragma unroll
  for (int r = 0; r < 2; ++r)
#pragma unroll
    for (int ii = 0; ii < 4; ++ii) rs[r][ii] = 0.f;
#pragma unroll
  for (int c = 0; c < 4; ++c) cs[c] = 0.f;
#pragma unroll
  for (int r = 0; r < 2; ++r)
#pragma unroll
    for (int c = 0; c < 4; ++c)
#pragma unroll
      for (int ii = 0; ii < 4; ++ii) {
        float v = tanh_safe(acc[r][c][ii]);
        rs[r][ii] += v;
        cs[c] += v;
      }
  // rows (held per (q,r,ii)): reduce across mlane bits
#pragma unroll
  for (int m = 1; m < 16; m <<= 1)
#pragma unroll
    for (int r = 0; r < 2; ++r)
#pragma unroll
      for (int ii = 0; ii < 4; ++ii) rs[r][ii] += __shfl_xor(rs[r][ii], m, 64);
  // cols (held per mlane,c): reduce across q bits
#pragma unroll
  for (int m = 16; m < 64; m <<= 1)
#pragma unroll
    for (int c = 0; c < 4; ++c) cs[c] += __shfl_xor(cs[c], m, 64);

  float* rsum = (float*)sm;          // [64]
  float* csum = ((float*)sm) + 64;   // [128]
  if (tid < 64) rsum[tid] = 0.f;
  else if (tid < 192) csum[tid - 64] = 0.f;
  __syncthreads();
  if (mlane == 0) {
#pragma unroll
    for (int r = 0; r < 2; ++r)
#pragma unroll
      for (int ii = 0; ii < 4; ++ii)
        atomicAdd(&rsum[wr * 32 + r * 16 + q * 4 + ii], rs[r][ii]);
  }
  if (q == 0) {
#pragma unroll
    for (int c = 0; c < 4; ++c) atomicAdd(&csum[wc * 64 + c * 16 + mlane], cs[c]);
  }
  __syncthreads();
  if (tid < 64)
    atomicAdd(&rowlog[b * S_ + by * 64 + tid], rsum[tid]);
  else if (tid < 192)
    atomicAdd(&collog[b * S_ + bx * 128 + (tid - 64)], csum[tid - 64]);
}

// ---------------- finalize ----------------
__device__ __forceinline__ float block_max(float v, float* buf, int tid) {
  buf[tid] = v; __syncthreads();
  for (int s = 128; s > 0; s >>= 1) {
    if (tid < s) buf[tid] = fmaxf(buf[tid], buf[tid + s]);
    __syncthreads();
  }
  float r = buf[0]; __syncthreads();
  return r;
}
__device__ __forceinline__ float block_sum(float v, float* buf, int tid) {
  buf[tid] = v; __syncthreads();
  for (int s = 128; s > 0; s >>= 1) {
    if (tid < s) buf[tid] = buf[tid] + buf[tid + s];
    __syncthreads();
  }
  float r = buf[0]; __syncthreads();
  return r;
}

__global__ __launch_bounds__(256) void finalize(
    const float* __restrict__ rowlog, const float* __restrict__ collog,
    const ushort* __restrict__ dg, const ushort* __restrict__ ug,
    float* __restrict__ out) {
  __shared__ float sd[S_], su[S_], buf[S_];
  const int b = blockIdx.x, tid = threadIdx.x;

  const float rowmean = rowlog[b * S_ + tid] * (1.f / (float)S_);
  const float colmean = collog[b * S_ + tid] * (1.f / (float)S_);

  float md = block_max(rowmean, buf, tid);
  float ed = __expf(rowmean - md);
  float sds = block_sum(ed, buf, tid);
  sd[tid] = ed / sds;
  float mu = block_max(colmean, buf, tid);
  float eu = __expf(colmean - mu);
  float sus = block_sum(eu, buf, tid);
  su[tid] = eu / sus;
  __syncthreads();

  const ushort* dgb = dg + (long)b * (S_ * OUT_F_);
  const ushort* ugb = ug + (long)b * (S_ * OUT_F_);
  float ad0 = 0.f, ad1 = 0.f, au0 = 0.f, au1 = 0.f;
  const int o = 2 * tid;
  for (int s = 0; s < S_; ++s) {
    const float wd = sd[s], wu = su[s];
    unsigned dv = *(const unsigned*)(dgb + s * OUT_F_ + o);
    unsigned uv = *(const unsigned*)(ugb + s * OUT_F_ + o);
    ad0 += wd * bf2f(dv & 0xffffu); ad1 += wd * bf2f(dv >> 16);
    au0 += wu * bf2f(uv & 0xffffu); au1 += wu * bf2f(uv >> 16);
  }
  out[b * OUT_F_ + o] = ad0;
  out[b * OUT_F_ + o + 1] = ad1;
  out[BSZ_ * OUT_F_ + b * OUT_F_ + o] = au0;
  out[BSZ_ * OUT_F_ + b * OUT_F_ + o + 1] = au1;
}

extern "C" void kernel_launch(void* const* d_in, const int* in_sizes, int n_in,
                              void* d_out, int out_size, void* d_ws, size_t ws_size,
                              hipStream_t stream) {
  (void)in_sizes; (void)n_in; (void)out_size; (void)ws_size;
  const float* Xd = (const float*)d_in[0];
  const float* Xu = (const float*)d_in[1];
  const float* Wd = (const float*)d_in[2];
  const float* bd = (const float*)d_in[3];
  const float* Wu = (const float*)d_in[4];
  const float* bu = (const float*)d_in[5];
  const float* W  = (const float*)d_in[6];
  float* out = (float*)d_out;
  char* ws = (char*)d_ws;

  ushort* Xd_bf  = (ushort*)(ws + 0L);
  ushort* Xu_bf  = (ushort*)(ws + 33554432L);
  ushort* Wd_bf  = (ushort*)(ws + 50331648L);
  ushort* Wu_bf  = (ushort*)(ws + 51380224L);
  ushort* Wt_bf  = (ushort*)(ws + 51904512L);
  ushort* dg     = (ushort*)(ws + 52428800L);
  ushort* ug     = (ushort*)(ws + 69206016L);
  ushort* t_bf   = (ushort*)(ws + 85983232L);
  float*  rowlog = (float*)(ws + 102760448L);
  float*  collog = (float*)(ws + 102825984L);

  convert_bf16<<<16384, 256, 0, stream>>>(Xd, Xd_bf, 16777216L);
  convert_bf16<<<8192, 256, 0, stream>>>(Xu, Xu_bf, 8388608L);
  convert_bf16<<<512, 256, 0, stream>>>(Wd, Wd_bf, 524288L);
  convert_bf16<<<256, 256, 0, stream>>>(Wu, Wu_bf, 262144L);
  convert_transpose_w<<<1024, 256, 0, stream>>>(W, Wt_bf);
  zerof<<<128, 256, 0, stream>>>(rowlog, 32768);

  dim3 blk(256);
  gemm_du<<<1024, blk, 0, stream>>>(Xd_bf, Wd_bf, bd, Xu_bf, Wu_bf, bu, dg, ug);
  gemm_t<<<1024, blk, 0, stream>>>(dg, Wt_bf, t_bf);
  gemm_att<<<512, blk, 0, stream>>>(t_bf, ug, rowlog, collog);
  finalize<<<64, 256, 0, stream>>>(rowlog, collog, dg, ug, out);
}